// Round 1
// baseline (5173.265 us; speedup 1.0000x reference)
//
#include <hip/hip_runtime.h>

#define NN 50000
#define NE 800000
#define CLAMPV 5.0f
#define BNS 0.9999950000374997f

// ---------------- degree / CSR build ----------------

__global__ __launch_bounds__(256) void k_deg(const int* __restrict__ ei, int* __restrict__ deg) {
    int e = blockIdx.x * 256 + threadIdx.x;
    if (e < NE) atomicAdd(&deg[ei[NE + e]], 1);
}

__global__ __launch_bounds__(1024) void k_scan(const int* __restrict__ deg, int* __restrict__ offs) {
    __shared__ int sm[1024];
    __shared__ int carry;
    if (threadIdx.x == 0) { carry = 0; offs[0] = 0; }
    __syncthreads();
    for (int base = 0; base < NN; base += 1024) {
        int i = base + threadIdx.x;
        int v = (i < NN) ? deg[i] : 0;
        sm[threadIdx.x] = v;
        __syncthreads();
        for (int s = 1; s < 1024; s <<= 1) {
            int t = (threadIdx.x >= s) ? sm[threadIdx.x - s] : 0;
            __syncthreads();
            sm[threadIdx.x] += t;
            __syncthreads();
        }
        if (i < NN) offs[i + 1] = carry + sm[threadIdx.x];
        __syncthreads();
        if (threadIdx.x == 0) carry += sm[1023];
        __syncthreads();
    }
}

__global__ __launch_bounds__(256) void k_fill(const int* __restrict__ ei, const int* __restrict__ offs,
                                              int* __restrict__ cursor, int* __restrict__ csr) {
    int e = blockIdx.x * 256 + threadIdx.x;
    if (e < NE) {
        int d = ei[NE + e];
        int pos = offs[d] + atomicAdd(&cursor[d], 1);
        csr[pos] = e;
    }
}

__global__ __launch_bounds__(256) void k_logdeg(const int* __restrict__ deg, float* __restrict__ logdeg) {
    int i = blockIdx.x * 256 + threadIdx.x;
    if (i < NN) logdeg[i] = logf((float)deg[i] + 1.0f);
}

// ---------------- per-layer kernels ----------------

// Q/K/V: 8 nodes per block, 256 threads. col = tid&127, half = tid>>7 handles 4 rows.
__global__ __launch_bounds__(256) void k_qkv(const float* __restrict__ x,
                                             const float* __restrict__ Wq, const float* __restrict__ bq,
                                             const float* __restrict__ Wk, const float* __restrict__ Wv,
                                             float* __restrict__ Qh, float* __restrict__ Kh, float* __restrict__ Vh) {
    __shared__ float xs[8][128];
    int n0 = blockIdx.x * 8;
    for (int t = threadIdx.x; t < 8 * 128; t += 256) {
        int r = t >> 7, c = t & 127;
        int n = n0 + r;
        xs[r][c] = (n < NN) ? x[(size_t)n * 128 + c] : 0.0f;
    }
    __syncthreads();
    int col = threadIdx.x & 127, half = threadIdx.x >> 7;
    float aq[4], ak[4], av[4];
    float bqv = bq[col];
#pragma unroll
    for (int r = 0; r < 4; ++r) { aq[r] = bqv; ak[r] = 0.0f; av[r] = 0.0f; }
    for (int k = 0; k < 128; ++k) {
        float wq = Wq[k * 128 + col];
        float wk = Wk[k * 128 + col];
        float wv = Wv[k * 128 + col];
#pragma unroll
        for (int r = 0; r < 4; ++r) {
            float xv = xs[half * 4 + r][k];
            aq[r] += xv * wq; ak[r] += xv * wk; av[r] += xv * wv;
        }
    }
#pragma unroll
    for (int r = 0; r < 4; ++r) {
        int n = n0 + half * 4 + r;
        if (n < NN) {
            Qh[(size_t)n * 128 + col] = aq[r];
            Kh[(size_t)n * 128 + col] = ak[r];
            Vh[(size_t)n * 128 + col] = av[r];
        }
    }
}

// Edge kernel A: Ep = ea @ We + be; e_t = relu(signed_sqrt((Kh[src]+Qh[dst])*E_w)+E_b);
// sc = clip(sum_d e_t*Aw). 16 edges/block.
__global__ __launch_bounds__(256) void k_edgeA(const float* __restrict__ ea, const int* __restrict__ ei,
                                               const float* __restrict__ We, const float* __restrict__ be,
                                               const float* __restrict__ Aw,
                                               const float* __restrict__ Qh, const float* __restrict__ Kh,
                                               float* __restrict__ e_t, float* __restrict__ sc) {
    __shared__ float eas[16][128];
    __shared__ float ep[16][256];
    __shared__ float ets[16][128];
    int e0 = blockIdx.x * 16;
    for (int t = threadIdx.x; t < 16 * 128; t += 256) {
        int r = t >> 7, c = t & 127;
        int e = e0 + r;
        eas[r][c] = (e < NE) ? ea[(size_t)e * 128 + c] : 0.0f;
    }
    __syncthreads();
    {   // Ep GEMM: 16x256, each thread owns one col across 16 rows
        float acc[16];
        float bb = be[threadIdx.x];
#pragma unroll
        for (int r = 0; r < 16; ++r) acc[r] = bb;
        for (int k = 0; k < 128; ++k) {
            float w = We[k * 256 + threadIdx.x];
#pragma unroll
            for (int r = 0; r < 16; ++r) acc[r] += eas[r][k] * w;
        }
#pragma unroll
        for (int r = 0; r < 16; ++r) ep[r][threadIdx.x] = acc[r];
    }
    __syncthreads();
    for (int t = threadIdx.x; t < 16 * 128; t += 256) {
        int r = t >> 7, c = t & 127;
        int e = e0 + r;
        if (e < NE) {
            int hh = c >> 4, d = c & 15;
            int si = ei[e], di = ei[NE + e];
            float sv = (Kh[(size_t)si * 128 + c] + Qh[(size_t)di * 128 + c]) * ep[r][hh * 32 + d];
            float ss = (sv > 0.0f) ? sqrtf(sv) : ((sv < 0.0f) ? -sqrtf(-sv) : 0.0f);
            ss += ep[r][hh * 32 + 16 + d];
            float et = fmaxf(ss, 0.0f);
            ets[r][c] = et;
            e_t[(size_t)e * 128 + c] = et;
        }
    }
    __syncthreads();
    if (threadIdx.x < 128) {
        int r = threadIdx.x >> 3, h = threadIdx.x & 7;
        int e = e0 + r;
        if (e < NE) {
            float s = 0.0f;
#pragma unroll
            for (int d = 0; d < 16; ++d) s += ets[r][h * 16 + d] * Aw[d * 8 + h];
            s = fminf(fmaxf(s, -CLAMPV), CLAMPV);
            sc[(size_t)e * 8 + h] = s;
        }
    }
}

// Node attention: one 64-lane wave per node. CSR gather: softmax (max, denom) per head,
// then accumulate wV and rowV. No atomics.
__global__ __launch_bounds__(64) void k_nattn(const int* __restrict__ offs, const int* __restrict__ csr,
                                              const int* __restrict__ ei, const float* __restrict__ sc,
                                              const float* __restrict__ e_t, const float* __restrict__ Vh,
                                              float* __restrict__ wV, float* __restrict__ rowV) {
    int n = blockIdx.x;
    int lane = threadIdx.x;
    int beg = offs[n], end = offs[n + 1];
    int h = lane & 7, es = lane >> 3;
    float m = -1e30f;
    for (int i = beg + es; i < end; i += 8) {
        int e = csr[i];
        m = fmaxf(m, sc[(size_t)e * 8 + h]);
    }
#pragma unroll
    for (int off = 8; off < 64; off <<= 1) m = fmaxf(m, __shfl_xor(m, off));
    float dsum = 0.0f;
    for (int i = beg + es; i < end; i += 8) {
        int e = csr[i];
        dsum += expf(sc[(size_t)e * 8 + h] - m);
    }
#pragma unroll
    for (int off = 8; off < 64; off <<= 1) dsum += __shfl_xor(dsum, off);
    float inv_d = 1.0f / (dsum + 1e-16f);

    int c0 = lane, c1 = lane + 64;
    int h0 = c0 >> 4, h1 = c1 >> 4;
    float m0 = __shfl(m, h0), m1 = __shfl(m, h1);
    float id0 = __shfl(inv_d, h0), id1 = __shfl(inv_d, h1);
    float av0 = 0.0f, av1 = 0.0f, ar0 = 0.0f, ar1 = 0.0f;
    for (int i = beg; i < end; ++i) {
        int e = csr[i];
        int s = ei[e];
        float a0 = expf(sc[(size_t)e * 8 + h0] - m0) * id0;
        float a1 = expf(sc[(size_t)e * 8 + h1] - m1) * id1;
        av0 += Vh[(size_t)s * 128 + c0] * a0;
        av1 += Vh[(size_t)s * 128 + c1] * a1;
        ar0 += e_t[(size_t)e * 128 + c0] * a0;
        ar1 += e_t[(size_t)e * 128 + c1] * a1;
    }
    wV[(size_t)n * 128 + c0] = av0;
    wV[(size_t)n * 128 + c1] = av1;
    rowV[(size_t)n * 128 + c0] = ar0;
    rowV[(size_t)n * 128 + c1] = ar1;
}

// Node post: h = wV + rowV@VeRow; deg scale; Woh; residual+BN; MLP; residual+BN. 8 nodes/block.
__global__ __launch_bounds__(256) void k_nodeB(const float* __restrict__ wV, const float* __restrict__ rowV,
                                               const float* __restrict__ VeRow, const float* __restrict__ dc,
                                               const float* __restrict__ logdeg, const float* __restrict__ x,
                                               const float* __restrict__ Woh, const float* __restrict__ boh,
                                               const float* __restrict__ W1, const float* __restrict__ b1,
                                               const float* __restrict__ W2, const float* __restrict__ b2,
                                               float* __restrict__ xout) {
    __shared__ float hs[8][128];
    __shared__ float hb[8][128];
    __shared__ float us[8][256];
    int n0 = blockIdx.x * 8;
    for (int t = threadIdx.x; t < 8 * 128; t += 256) {
        int r = t >> 7, c = t & 127;
        int n = n0 + r;
        if (n < NN) {
            int hh = c >> 4, d = c & 15;
            float acc = wV[(size_t)n * 128 + c];
#pragma unroll
            for (int dd = 0; dd < 16; ++dd)
                acc += rowV[(size_t)n * 128 + hh * 16 + dd] * VeRow[dd * 128 + hh * 16 + d];
            float ld = logdeg[n];
            acc = acc * (dc[c * 2 + 0] + ld * dc[c * 2 + 1]);
            hs[r][c] = acc;
        } else {
            hs[r][c] = 0.0f;
        }
    }
    __syncthreads();
    int col = threadIdx.x & 127, half = threadIdx.x >> 7;
    {   // hb = (x + hs@Woh + boh) * BNS
        float acc[4];
        float bb = boh[col];
#pragma unroll
        for (int r = 0; r < 4; ++r) acc[r] = bb;
        for (int k = 0; k < 128; ++k) {
            float w = Woh[k * 128 + col];
#pragma unroll
            for (int r = 0; r < 4; ++r) acc[r] += hs[half * 4 + r][k] * w;
        }
#pragma unroll
        for (int r = 0; r < 4; ++r) {
            int n = n0 + half * 4 + r;
            float xv = (n < NN) ? x[(size_t)n * 128 + col] : 0.0f;
            hb[half * 4 + r][col] = (xv + acc[r]) * BNS;
        }
    }
    __syncthreads();
    {   // us = relu(hb@W1 + b1): each thread one of 256 cols, 8 rows
        float acc[8];
        float bb = b1[threadIdx.x];
#pragma unroll
        for (int r = 0; r < 8; ++r) acc[r] = bb;
        for (int k = 0; k < 128; ++k) {
            float w = W1[k * 256 + threadIdx.x];
#pragma unroll
            for (int r = 0; r < 8; ++r) acc[r] += hb[r][k] * w;
        }
#pragma unroll
        for (int r = 0; r < 8; ++r) us[r][threadIdx.x] = fmaxf(acc[r], 0.0f);
    }
    __syncthreads();
    {   // h2 = us@W2 + b2; out = (hb + h2) * BNS
        float acc[4];
        float bb = b2[col];
#pragma unroll
        for (int r = 0; r < 4; ++r) acc[r] = bb;
        for (int k = 0; k < 256; ++k) {
            float w = W2[k * 128 + col];
#pragma unroll
            for (int r = 0; r < 4; ++r) acc[r] += us[half * 4 + r][k] * w;
        }
#pragma unroll
        for (int r = 0; r < 4; ++r) {
            int n = n0 + half * 4 + r;
            if (n < NN) xout[(size_t)n * 128 + col] = (hb[half * 4 + r][col] + acc[r]) * BNS;
        }
    }
}

// Edge out: e = (ea + e_t@Woe + boe) * BNS. 16 edges/block. Safe in-place (row read by owning thread first).
__global__ __launch_bounds__(256) void k_edgeC(const float* __restrict__ e_t, const float* __restrict__ ea,
                                               const float* __restrict__ Woe, const float* __restrict__ boe,
                                               float* __restrict__ eout) {
    __shared__ float ets[16][128];
    int e0 = blockIdx.x * 16;
    for (int t = threadIdx.x; t < 16 * 128; t += 256) {
        int r = t >> 7, c = t & 127;
        int e = e0 + r;
        ets[r][c] = (e < NE) ? e_t[(size_t)e * 128 + c] : 0.0f;
    }
    __syncthreads();
    int col = threadIdx.x & 127, half = threadIdx.x >> 7;
    float acc[8];
    float bb = boe[col];
#pragma unroll
    for (int r = 0; r < 8; ++r) acc[r] = bb;
    for (int k = 0; k < 128; ++k) {
        float w = Woe[k * 128 + col];
#pragma unroll
        for (int r = 0; r < 8; ++r) acc[r] += ets[half * 8 + r][k] * w;
    }
#pragma unroll
    for (int r = 0; r < 8; ++r) {
        int e = e0 + half * 8 + r;
        if (e < NE) {
            size_t idx = (size_t)e * 128 + col;
            float res = ea[idx];
            eout[idx] = (res + acc[r]) * BNS;
        }
    }
}

// ---------------- host launch ----------------

extern "C" void kernel_launch(void* const* d_in, const int* in_sizes, int n_in,
                              void* d_out, int out_size, void* d_ws, size_t ws_size,
                              hipStream_t stream) {
    (void)in_sizes; (void)n_in; (void)out_size; (void)ws_size;
    const float* x_in0  = (const float*)d_in[0];
    const int*   ei     = (const int*)d_in[1];
    const float* ea_in0 = (const float*)d_in[2];
    const float* Wq = (const float*)d_in[3];
    const float* bq = (const float*)d_in[4];
    const float* Wk = (const float*)d_in[5];
    const float* Wv = (const float*)d_in[6];
    const float* We = (const float*)d_in[7];
    const float* be = (const float*)d_in[8];
    const float* Aw = (const float*)d_in[9];
    const float* VeRow = (const float*)d_in[10];
    const float* Woh = (const float*)d_in[11];
    const float* boh = (const float*)d_in[12];
    const float* Woe = (const float*)d_in[13];
    const float* boe = (const float*)d_in[14];
    const float* dc  = (const float*)d_in[15];
    const float* W1 = (const float*)d_in[16];
    const float* b1 = (const float*)d_in[17];
    const float* W2 = (const float*)d_in[18];
    const float* b2 = (const float*)d_in[19];

    char* ws = (char*)d_ws;
    size_t off = 0;
    auto alloc = [&](size_t bytes) { void* p = ws + off; off = (off + bytes + 255) & ~(size_t)255; return p; };
    int*   deg    = (int*)alloc((size_t)NN * 4);
    int*   cursor = (int*)alloc((size_t)NN * 4);
    int*   offs   = (int*)alloc((size_t)(NN + 1) * 4);
    int*   csr    = (int*)alloc((size_t)NE * 4);
    float* logdeg = (float*)alloc((size_t)NN * 4);
    float* Qh     = (float*)alloc((size_t)NN * 128 * 4);
    float* Kh     = (float*)alloc((size_t)NN * 128 * 4);
    float* Vh     = (float*)alloc((size_t)NN * 128 * 4);
    float* e_t    = (float*)alloc((size_t)NE * 128 * 4);
    float* sc     = (float*)alloc((size_t)NE * 8 * 4);
    float* wV     = (float*)alloc((size_t)NN * 128 * 4);
    float* rowV   = (float*)alloc((size_t)NN * 128 * 4);

    float* out_x = (float*)d_out;
    float* out_e = out_x + (size_t)NN * 128;

    hipMemsetAsync(deg, 0, (size_t)NN * 4, stream);
    hipMemsetAsync(cursor, 0, (size_t)NN * 4, stream);

    k_deg<<<(NE + 255) / 256, 256, 0, stream>>>(ei, deg);
    k_scan<<<1, 1024, 0, stream>>>(deg, offs);
    k_fill<<<(NE + 255) / 256, 256, 0, stream>>>(ei, offs, cursor, csr);
    k_logdeg<<<(NN + 255) / 256, 256, 0, stream>>>(deg, logdeg);

    for (int l = 0; l < 2; ++l) {
        const float* x_l  = (l == 0) ? x_in0 : out_x;
        const float* ea_l = (l == 0) ? ea_in0 : out_e;
        const float* Wq_l = Wq + (size_t)l * 128 * 128;
        const float* bq_l = bq + (size_t)l * 128;
        const float* Wk_l = Wk + (size_t)l * 128 * 128;
        const float* Wv_l = Wv + (size_t)l * 128 * 128;
        const float* We_l = We + (size_t)l * 128 * 256;
        const float* be_l = be + (size_t)l * 256;
        const float* Aw_l = Aw + (size_t)l * 16 * 8;
        const float* VeRow_l = VeRow + (size_t)l * 16 * 8 * 16;
        const float* Woh_l = Woh + (size_t)l * 128 * 128;
        const float* boh_l = boh + (size_t)l * 128;
        const float* Woe_l = Woe + (size_t)l * 128 * 128;
        const float* boe_l = boe + (size_t)l * 128;
        const float* dc_l  = dc + (size_t)l * 128 * 2;
        const float* W1_l = W1 + (size_t)l * 128 * 256;
        const float* b1_l = b1 + (size_t)l * 256;
        const float* W2_l = W2 + (size_t)l * 256 * 128;
        const float* b2_l = b2 + (size_t)l * 128;

        k_qkv<<<NN / 8, 256, 0, stream>>>(x_l, Wq_l, bq_l, Wk_l, Wv_l, Qh, Kh, Vh);
        k_edgeA<<<NE / 16, 256, 0, stream>>>(ea_l, ei, We_l, be_l, Aw_l, Qh, Kh, e_t, sc);
        k_nattn<<<NN, 64, 0, stream>>>(offs, csr, ei, sc, e_t, Vh, wV, rowV);
        k_nodeB<<<NN / 8, 256, 0, stream>>>(wV, rowV, VeRow_l, dc_l, logdeg, x_l,
                                            Woh_l, boh_l, W1_l, b1_l, W2_l, b2_l, out_x);
        k_edgeC<<<NE / 16, 256, 0, stream>>>(e_t, ea_l, Woe_l, boe_l, out_e);
    }
}

// Round 2
// 2294.468 us; speedup vs baseline: 2.2547x; 2.2547x over previous
//
#include <hip/hip_runtime.h>

#define NN 50000
#define NE 800000
#define CLAMPV 5.0f
#define BNS 0.9999950000374997f

typedef __attribute__((ext_vector_type(8))) short s16x8;
typedef __attribute__((ext_vector_type(8))) __bf16 bf16x8;
typedef __attribute__((ext_vector_type(4))) float f32x4;

__device__ inline f32x4 mfma16(s16x8 a, s16x8 b, f32x4 c) {
    return __builtin_amdgcn_mfma_f32_16x16x32_bf16(
        __builtin_bit_cast(bf16x8, a), __builtin_bit_cast(bf16x8, b), c, 0, 0, 0);
}

__device__ inline unsigned short bf16r(float f) {
    unsigned u = __builtin_bit_cast(unsigned, f);
    return (unsigned short)((u + 0x7FFFu + ((u >> 16) & 1u)) >> 16);
}

// ---------------- degree / CSR build ----------------

__global__ __launch_bounds__(256) void k_deg(const int* __restrict__ ei, int* __restrict__ deg) {
    int e = blockIdx.x * 256 + threadIdx.x;
    if (e < NE) atomicAdd(&deg[ei[NE + e]], 1);
}

__global__ __launch_bounds__(1024) void k_scan(const int* __restrict__ deg, int* __restrict__ offs) {
    __shared__ int sm[1024];
    __shared__ int carry;
    if (threadIdx.x == 0) { carry = 0; offs[0] = 0; }
    __syncthreads();
    for (int base = 0; base < NN; base += 1024) {
        int i = base + threadIdx.x;
        int v = (i < NN) ? deg[i] : 0;
        sm[threadIdx.x] = v;
        __syncthreads();
        for (int s = 1; s < 1024; s <<= 1) {
            int t = (threadIdx.x >= s) ? sm[threadIdx.x - s] : 0;
            __syncthreads();
            sm[threadIdx.x] += t;
            __syncthreads();
        }
        if (i < NN) offs[i + 1] = carry + sm[threadIdx.x];
        __syncthreads();
        if (threadIdx.x == 0) carry += sm[1023];
        __syncthreads();
    }
}

__global__ __launch_bounds__(256) void k_fill(const int* __restrict__ ei, const int* __restrict__ offs,
                                              int* __restrict__ cursor, int* __restrict__ csr) {
    int e = blockIdx.x * 256 + threadIdx.x;
    if (e < NE) {
        int d = ei[NE + e];
        int pos = offs[d] + atomicAdd(&cursor[d], 1);
        csr[pos] = e;
    }
}

__global__ __launch_bounds__(256) void k_logdeg(const int* __restrict__ deg, float* __restrict__ logdeg) {
    int i = blockIdx.x * 256 + threadIdx.x;
    if (i < NN) logdeg[i] = logf((float)deg[i] + 1.0f);
}

// Pack fp32 weight W[k][col] (k=0..127, col=0..ncol-1) into MFMA B-fragment order:
// out[((kt*ncol + col)*4 + kg)*8 + j] = bf16(W[(kt*32 + kg*8 + j)*ncol + col])
__global__ __launch_bounds__(256) void k_pack(const float* __restrict__ W, int ncol, short* __restrict__ out) {
    int idx = blockIdx.x * 256 + threadIdx.x;
    if (idx >= 128 * ncol) return;
    int j = idx & 7; int t = idx >> 3; int kg = t & 3; t >>= 2;
    int col = t % ncol; int kt = t / ncol;
    int k = kt * 32 + kg * 8 + j;
    float v = W[k * ncol + col];
    out[idx] = (short)bf16r(v);
}

// ---------------- per-layer kernels ----------------

// Q/K/V: 8 nodes per block, 256 threads (fp32 VALU).
__global__ __launch_bounds__(256) void k_qkv(const float* __restrict__ x,
                                             const float* __restrict__ Wq, const float* __restrict__ bq,
                                             const float* __restrict__ Wk, const float* __restrict__ Wv,
                                             float* __restrict__ Qh, float* __restrict__ Kh, float* __restrict__ Vh) {
    __shared__ float xs[8][128];
    int n0 = blockIdx.x * 8;
    for (int t = threadIdx.x; t < 8 * 128; t += 256) {
        int r = t >> 7, c = t & 127;
        int n = n0 + r;
        xs[r][c] = (n < NN) ? x[(size_t)n * 128 + c] : 0.0f;
    }
    __syncthreads();
    int col = threadIdx.x & 127, half = threadIdx.x >> 7;
    float aq[4], ak[4], av[4];
    float bqv = bq[col];
#pragma unroll
    for (int r = 0; r < 4; ++r) { aq[r] = bqv; ak[r] = 0.0f; av[r] = 0.0f; }
    for (int k = 0; k < 128; ++k) {
        float wq = Wq[k * 128 + col];
        float wk = Wk[k * 128 + col];
        float wv = Wv[k * 128 + col];
#pragma unroll
        for (int r = 0; r < 4; ++r) {
            float xv = xs[half * 4 + r][k];
            aq[r] += xv * wq; ak[r] += xv * wk; av[r] += xv * wv;
        }
    }
#pragma unroll
    for (int r = 0; r < 4; ++r) {
        int n = n0 + half * 4 + r;
        if (n < NN) {
            Qh[(size_t)n * 128 + col] = aq[r];
            Kh[(size_t)n * 128 + col] = ak[r];
            Vh[(size_t)n * 128 + col] = av[r];
        }
    }
}

// Edge kernel A (MFMA): Ep = ea@We + be; e_t = relu(signed_sqrt((Kh[src]+Qh[dst])*E_w)+E_b);
// sc = clip(sum_d e_t*Aw). 16 edges/block, 4 waves.
__global__ __launch_bounds__(256) void k_edgeA(const float* __restrict__ ea, const int* __restrict__ ei,
                                               const short* __restrict__ Wep, const float* __restrict__ be,
                                               const float* __restrict__ Aw,
                                               const float* __restrict__ Qh, const float* __restrict__ Kh,
                                               unsigned short* __restrict__ e_t, float* __restrict__ sc) {
    __shared__ short eas[16 * 128];
    __shared__ float ep[16 * 257];
    int e0 = blockIdx.x * 16;
    int t = threadIdx.x;
    int r = t >> 4, ci = t & 15;
    {   // stage ea tile -> bf16, XOR-swizzled LDS (G4: break stride-256B bank aliasing)
        const float4* src = (const float4*)(ea + (size_t)(e0 + r) * 128 + ci * 8);
        float4 v0 = src[0], v1 = src[1];
        union { unsigned short us[8]; int4 v; } pk;
        pk.us[0] = bf16r(v0.x); pk.us[1] = bf16r(v0.y); pk.us[2] = bf16r(v0.z); pk.us[3] = bf16r(v0.w);
        pk.us[4] = bf16r(v1.x); pk.us[5] = bf16r(v1.y); pk.us[6] = bf16r(v1.z); pk.us[7] = bf16r(v1.w);
        int byte = (r * 256 + ci * 16) ^ ((r & 7) << 4);
        *(int4*)((char*)eas + byte) = pk.v;
    }
    __syncthreads();
    {   // MFMA: 16x256 = 4 waves x 4 col-tiles, K=128 in 4 steps
        int lane = t & 63, w = t >> 6;
        int l15 = lane & 15, kg = lane >> 4;
        f32x4 acc[4];
#pragma unroll
        for (int q = 0; q < 4; ++q) { acc[q][0] = 0.f; acc[q][1] = 0.f; acc[q][2] = 0.f; acc[q][3] = 0.f; }
#pragma unroll
        for (int kt = 0; kt < 4; ++kt) {
            int abyte = (l15 * 256 + kt * 64 + kg * 16) ^ ((l15 & 7) << 4);
            s16x8 a = *(const s16x8*)((const char*)eas + abyte);
#pragma unroll
            for (int q = 0; q < 4; ++q) {
                int col = (w * 4 + q) * 16 + l15;
                s16x8 b = *(const s16x8*)(Wep + ((size_t)((kt * 256 + col) * 4 + kg)) * 8);
                acc[q] = mfma16(a, b, acc[q]);
            }
        }
#pragma unroll
        for (int q = 0; q < 4; ++q) {
            int col = (w * 4 + q) * 16 + l15;
            float bb = be[col];
#pragma unroll
            for (int i = 0; i < 4; ++i)
                ep[(kg * 4 + i) * 257 + col] = acc[q][i] + bb;   // row = C/D map (verified m89)
        }
    }
    __syncthreads();
    {   // elementwise: thread t handles edge r, cols ci*8..ci*8+7
        int e = e0 + r;
        int si = ei[e], di = ei[NE + e];
        int c0 = ci * 8;
        const float4* kp = (const float4*)(Kh + (size_t)si * 128 + c0);
        const float4* qp = (const float4*)(Qh + (size_t)di * 128 + c0);
        float4 ka = kp[0], kb = kp[1], qa = qp[0], qb = qp[1];
        float kq[8] = {ka.x + qa.x, ka.y + qa.y, ka.z + qa.z, ka.w + qa.w,
                       kb.x + qb.x, kb.y + qb.y, kb.z + qb.z, kb.w + qb.w};
        int hh = ci >> 1;            // head
        int dbase = (ci & 1) * 8;    // d offset within head
        float p = 0.f;
        union { unsigned short us[8]; int4 v; } pk;
#pragma unroll
        for (int j = 0; j < 8; ++j) {
            float ew = ep[r * 257 + hh * 32 + dbase + j];
            float ebv = ep[r * 257 + hh * 32 + 16 + dbase + j];
            float sv = kq[j] * ew;
            float ss = (sv > 0.f) ? sqrtf(sv) : ((sv < 0.f) ? -sqrtf(-sv) : 0.f);
            float et = fmaxf(ss + ebv, 0.f);
            p += et * Aw[(dbase + j) * 8 + hh];
            pk.us[j] = bf16r(et);
        }
        *(int4*)(e_t + (size_t)e * 128 + c0) = pk.v;
        p += __shfl_xor(p, 1);
        if ((ci & 1) == 0) {
            float s = fminf(fmaxf(p, -CLAMPV), CLAMPV);
            sc[(size_t)e * 8 + hh] = s;
        }
    }
}

// Node attention: one 64-lane wave per node, CSR gather, no atomics. e_t is bf16.
__global__ __launch_bounds__(64) void k_nattn(const int* __restrict__ offs, const int* __restrict__ csr,
                                              const int* __restrict__ ei, const float* __restrict__ sc,
                                              const unsigned short* __restrict__ e_t, const float* __restrict__ Vh,
                                              float* __restrict__ wV, float* __restrict__ rowV) {
    int n = blockIdx.x;
    int lane = threadIdx.x;
    int beg = offs[n], end = offs[n + 1];
    int h = lane & 7, es = lane >> 3;
    float m = -1e30f;
    for (int i = beg + es; i < end; i += 8) {
        int e = csr[i];
        m = fmaxf(m, sc[(size_t)e * 8 + h]);
    }
#pragma unroll
    for (int off = 8; off < 64; off <<= 1) m = fmaxf(m, __shfl_xor(m, off));
    float dsum = 0.0f;
    for (int i = beg + es; i < end; i += 8) {
        int e = csr[i];
        dsum += expf(sc[(size_t)e * 8 + h] - m);
    }
#pragma unroll
    for (int off = 8; off < 64; off <<= 1) dsum += __shfl_xor(dsum, off);
    float inv_d = 1.0f / (dsum + 1e-16f);

    int c0 = lane, c1 = lane + 64;
    int h0 = c0 >> 4, h1 = c1 >> 4;
    float m0 = __shfl(m, h0), m1 = __shfl(m, h1);
    float id0 = __shfl(inv_d, h0), id1 = __shfl(inv_d, h1);
    float av0 = 0.0f, av1 = 0.0f, ar0 = 0.0f, ar1 = 0.0f;
    for (int i = beg; i < end; ++i) {
        int e = csr[i];
        int s = ei[e];
        float a0 = expf(sc[(size_t)e * 8 + h0] - m0) * id0;
        float a1 = expf(sc[(size_t)e * 8 + h1] - m1) * id1;
        av0 += Vh[(size_t)s * 128 + c0] * a0;
        av1 += Vh[(size_t)s * 128 + c1] * a1;
        float t0 = __builtin_bit_cast(float, (unsigned)e_t[(size_t)e * 128 + c0] << 16);
        float t1 = __builtin_bit_cast(float, (unsigned)e_t[(size_t)e * 128 + c1] << 16);
        ar0 += t0 * a0;
        ar1 += t1 * a1;
    }
    wV[(size_t)n * 128 + c0] = av0;
    wV[(size_t)n * 128 + c1] = av1;
    rowV[(size_t)n * 128 + c0] = ar0;
    rowV[(size_t)n * 128 + c1] = ar1;
}

// Node post: h = wV + rowV@VeRow; deg scale; Woh; residual+BN; MLP; residual+BN. 8 nodes/block (fp32).
__global__ __launch_bounds__(256) void k_nodeB(const float* __restrict__ wV, const float* __restrict__ rowV,
                                               const float* __restrict__ VeRow, const float* __restrict__ dc,
                                               const float* __restrict__ logdeg, const float* __restrict__ x,
                                               const float* __restrict__ Woh, const float* __restrict__ boh,
                                               const float* __restrict__ W1, const float* __restrict__ b1,
                                               const float* __restrict__ W2, const float* __restrict__ b2,
                                               float* __restrict__ xout) {
    __shared__ float hs[8][128];
    __shared__ float hb[8][128];
    __shared__ float us[8][256];
    int n0 = blockIdx.x * 8;
    for (int t = threadIdx.x; t < 8 * 128; t += 256) {
        int r = t >> 7, c = t & 127;
        int n = n0 + r;
        if (n < NN) {
            int hh = c >> 4, d = c & 15;
            float acc = wV[(size_t)n * 128 + c];
#pragma unroll
            for (int dd = 0; dd < 16; ++dd)
                acc += rowV[(size_t)n * 128 + hh * 16 + dd] * VeRow[dd * 128 + hh * 16 + d];
            float ld = logdeg[n];
            acc = acc * (dc[c * 2 + 0] + ld * dc[c * 2 + 1]);
            hs[r][c] = acc;
        } else {
            hs[r][c] = 0.0f;
        }
    }
    __syncthreads();
    int col = threadIdx.x & 127, half = threadIdx.x >> 7;
    {
        float acc[4];
        float bb = boh[col];
#pragma unroll
        for (int r = 0; r < 4; ++r) acc[r] = bb;
        for (int k = 0; k < 128; ++k) {
            float w = Woh[k * 128 + col];
#pragma unroll
            for (int r = 0; r < 4; ++r) acc[r] += hs[half * 4 + r][k] * w;
        }
#pragma unroll
        for (int r = 0; r < 4; ++r) {
            int n = n0 + half * 4 + r;
            float xv = (n < NN) ? x[(size_t)n * 128 + col] : 0.0f;
            hb[half * 4 + r][col] = (xv + acc[r]) * BNS;
        }
    }
    __syncthreads();
    {
        float acc[8];
        float bb = b1[threadIdx.x];
#pragma unroll
        for (int r = 0; r < 8; ++r) acc[r] = bb;
        for (int k = 0; k < 128; ++k) {
            float w = W1[k * 256 + threadIdx.x];
#pragma unroll
            for (int r = 0; r < 8; ++r) acc[r] += hb[r][k] * w;
        }
#pragma unroll
        for (int r = 0; r < 8; ++r) us[r][threadIdx.x] = fmaxf(acc[r], 0.0f);
    }
    __syncthreads();
    {
        float acc[4];
        float bb = b2[col];
#pragma unroll
        for (int r = 0; r < 4; ++r) acc[r] = bb;
        for (int k = 0; k < 256; ++k) {
            float w = W2[k * 128 + col];
#pragma unroll
            for (int r = 0; r < 4; ++r) acc[r] += us[half * 4 + r][k] * w;
        }
#pragma unroll
        for (int r = 0; r < 4; ++r) {
            int n = n0 + half * 4 + r;
            if (n < NN) xout[(size_t)n * 128 + col] = (hb[half * 4 + r][col] + acc[r]) * BNS;
        }
    }
}

// Edge out (MFMA): e = (ea + e_t@Woe + boe) * BNS. 16 edges/block, 4 waves.
__global__ __launch_bounds__(256) void k_edgeC(const unsigned short* __restrict__ e_t, const float* __restrict__ ea,
                                               const short* __restrict__ Woep, const float* __restrict__ boe,
                                               float* __restrict__ eout) {
    __shared__ short ets[16 * 128];
    int e0 = blockIdx.x * 16;
    int t = threadIdx.x;
    int r = t >> 4, ci = t & 15;
    {
        int4 v = *(const int4*)(e_t + (size_t)(e0 + r) * 128 + ci * 8);
        int byte = (r * 256 + ci * 16) ^ ((r & 7) << 4);
        *(int4*)((char*)ets + byte) = v;
    }
    __syncthreads();
    int lane = t & 63, w = t >> 6;
    int l15 = lane & 15, kg = lane >> 4;
    f32x4 acc[2];
#pragma unroll
    for (int q = 0; q < 2; ++q) { acc[q][0] = 0.f; acc[q][1] = 0.f; acc[q][2] = 0.f; acc[q][3] = 0.f; }
#pragma unroll
    for (int kt = 0; kt < 4; ++kt) {
        int abyte = (l15 * 256 + kt * 64 + kg * 16) ^ ((l15 & 7) << 4);
        s16x8 a = *(const s16x8*)((const char*)ets + abyte);
#pragma unroll
        for (int q = 0; q < 2; ++q) {
            int col = (w * 2 + q) * 16 + l15;
            s16x8 b = *(const s16x8*)(Woep + ((size_t)((kt * 128 + col) * 4 + kg)) * 8);
            acc[q] = mfma16(a, b, acc[q]);
        }
    }
#pragma unroll
    for (int q = 0; q < 2; ++q) {
        int col = (w * 2 + q) * 16 + l15;
        float bb = boe[col];
#pragma unroll
        for (int i = 0; i < 4; ++i) {
            int rr = kg * 4 + i;
            size_t idx = (size_t)(e0 + rr) * 128 + col;
            eout[idx] = (ea[idx] + acc[q][i] + bb) * BNS;
        }
    }
}

// ---------------- host launch ----------------

extern "C" void kernel_launch(void* const* d_in, const int* in_sizes, int n_in,
                              void* d_out, int out_size, void* d_ws, size_t ws_size,
                              hipStream_t stream) {
    (void)in_sizes; (void)n_in; (void)out_size; (void)ws_size;
    const float* x_in0  = (const float*)d_in[0];
    const int*   ei     = (const int*)d_in[1];
    const float* ea_in0 = (const float*)d_in[2];
    const float* Wq = (const float*)d_in[3];
    const float* bq = (const float*)d_in[4];
    const float* Wk = (const float*)d_in[5];
    const float* Wv = (const float*)d_in[6];
    const float* We = (const float*)d_in[7];
    const float* be = (const float*)d_in[8];
    const float* Aw = (const float*)d_in[9];
    const float* VeRow = (const float*)d_in[10];
    const float* Woh = (const float*)d_in[11];
    const float* boh = (const float*)d_in[12];
    const float* Woe = (const float*)d_in[13];
    const float* boe = (const float*)d_in[14];
    const float* dc  = (const float*)d_in[15];
    const float* W1 = (const float*)d_in[16];
    const float* b1 = (const float*)d_in[17];
    const float* W2 = (const float*)d_in[18];
    const float* b2 = (const float*)d_in[19];

    char* ws = (char*)d_ws;
    size_t off = 0;
    auto alloc = [&](size_t bytes) { void* p = ws + off; off = (off + bytes + 255) & ~(size_t)255; return p; };
    int*   deg    = (int*)alloc((size_t)NN * 4);
    int*   cursor = (int*)alloc((size_t)NN * 4);
    int*   offs   = (int*)alloc((size_t)(NN + 1) * 4);
    int*   csr    = (int*)alloc((size_t)NE * 4);
    float* logdeg = (float*)alloc((size_t)NN * 4);
    float* Qh     = (float*)alloc((size_t)NN * 128 * 4);
    float* Kh     = (float*)alloc((size_t)NN * 128 * 4);
    float* Vh     = (float*)alloc((size_t)NN * 128 * 4);
    unsigned short* e_t = (unsigned short*)alloc((size_t)NE * 128 * 2);
    float* sc     = (float*)alloc((size_t)NE * 8 * 4);
    float* wV     = (float*)alloc((size_t)NN * 128 * 4);
    float* rowV   = (float*)alloc((size_t)NN * 128 * 4);
    short* Wep    = (short*)alloc((size_t)2 * 128 * 256 * 2);
    short* Woep   = (short*)alloc((size_t)2 * 128 * 128 * 2);

    float* out_x = (float*)d_out;
    float* out_e = out_x + (size_t)NN * 128;

    hipMemsetAsync(deg, 0, (size_t)NN * 4, stream);
    hipMemsetAsync(cursor, 0, (size_t)NN * 4, stream);

    k_deg<<<(NE + 255) / 256, 256, 0, stream>>>(ei, deg);
    k_scan<<<1, 1024, 0, stream>>>(deg, offs);
    k_fill<<<(NE + 255) / 256, 256, 0, stream>>>(ei, offs, cursor, csr);
    k_logdeg<<<(NN + 255) / 256, 256, 0, stream>>>(deg, logdeg);

    // pack We (128x256) and Woe (128x128) for both layers into MFMA B-fragment order
    k_pack<<<(128 * 256 + 255) / 256, 256, 0, stream>>>(We, 256, Wep);
    k_pack<<<(128 * 256 + 255) / 256, 256, 0, stream>>>(We + 128 * 256, 256, Wep + 128 * 256);
    k_pack<<<(128 * 128 + 255) / 256, 256, 0, stream>>>(Woe, 128, Woep);
    k_pack<<<(128 * 128 + 255) / 256, 256, 0, stream>>>(Woe + 128 * 128, 128, Woep + 128 * 128);

    for (int l = 0; l < 2; ++l) {
        const float* x_l  = (l == 0) ? x_in0 : out_x;
        const float* ea_l = (l == 0) ? ea_in0 : out_e;
        const float* Wq_l = Wq + (size_t)l * 128 * 128;
        const float* bq_l = bq + (size_t)l * 128;
        const float* Wk_l = Wk + (size_t)l * 128 * 128;
        const float* Wv_l = Wv + (size_t)l * 128 * 128;
        const short* Wep_l = Wep + (size_t)l * 128 * 256;
        const float* be_l = be + (size_t)l * 256;
        const float* Aw_l = Aw + (size_t)l * 16 * 8;
        const float* VeRow_l = VeRow + (size_t)l * 16 * 8 * 16;
        const float* Woh_l = Woh + (size_t)l * 128 * 128;
        const float* boh_l = boh + (size_t)l * 128;
        const short* Woep_l = Woep + (size_t)l * 128 * 128;
        const float* boe_l = boe + (size_t)l * 128;
        const float* dc_l  = dc + (size_t)l * 128 * 2;
        const float* W1_l = W1 + (size_t)l * 128 * 256;
        const float* b1_l = b1 + (size_t)l * 256;
        const float* W2_l = W2 + (size_t)l * 256 * 128;
        const float* b2_l = b2 + (size_t)l * 128;

        k_qkv<<<NN / 8, 256, 0, stream>>>(x_l, Wq_l, bq_l, Wk_l, Wv_l, Qh, Kh, Vh);
        k_edgeA<<<NE / 16, 256, 0, stream>>>(ea_l, ei, Wep_l, be_l, Aw_l, Qh, Kh, e_t, sc);
        k_nattn<<<NN, 64, 0, stream>>>(offs, csr, ei, sc, e_t, Vh, wV, rowV);
        k_nodeB<<<NN / 8, 256, 0, stream>>>(wV, rowV, VeRow_l, dc_l, logdeg, x_l,
                                            Woh_l, boh_l, W1_l, b1_l, W2_l, b2_l, out_x);
        k_edgeC<<<NE / 16, 256, 0, stream>>>(e_t, ea_l, Woep_l, boe_l, out_e);
    }
}